// Round 1
// baseline (79.250 us; speedup 1.0000x reference)
//
#include <hip/hip_runtime.h>
#include <hip/hip_bf16.h>

// out[b,n,u] = sum_t x[b,n,t] * W_eff[u,t] + b_eff[u]
//   W_eff = Ws + (Wt - Ws) @ A   (A = causal window-mean operator, window 25)
//   b_eff = tb + sb
// M = 32*512 = 16384, T = 720.  Kp = 736 (23*32) zero-padded, Wrows = 768 padded.

#define Tdim  720
#define KP    736
#define WROWS 768

using bf16x8 = __attribute__((ext_vector_type(8))) __bf16;
using f32x4  = __attribute__((ext_vector_type(4))) float;

__global__ void fold_w_kernel(const float* __restrict__ tw,
                              const float* __restrict__ tb,
                              const float* __restrict__ sw,
                              const float* __restrict__ sb,
                              __bf16* __restrict__ Wb,
                              float* __restrict__ beff) {
  int idx = blockIdx.x * 256 + threadIdx.x;
  if (idx >= WROWS * KP) return;
  int u = idx / KP;
  int i = idx - u * KP;
  float w = 0.0f;
  if (u < Tdim && i < Tdim) {
    const float* twr = tw + (size_t)u * Tdim;
    const float* swr = sw + (size_t)u * Tdim;
    int tend = (i + 25 < Tdim) ? (i + 25) : Tdim;
    float acc = 0.0f;
    if (i >= 24) {
      // all counts in window are 25
      #pragma unroll 5
      for (int t = i; t < tend; ++t) acc += twr[t] - swr[t];
      acc *= 0.04f;
    } else {
      for (int t = i; t < tend; ++t) {
        float c = (t >= 24) ? 0.04f : 1.0f / (float)(t + 1);
        acc += (twr[t] - swr[t]) * c;
      }
    }
    w = swr[i] + acc;
  }
  Wb[idx] = (__bf16)w;
  if (i == 0 && u < Tdim) beff[u] = tb[u] + sb[u];
}

__global__ __launch_bounds__(256, 3)
void dlinear_gemm(const float* __restrict__ x,
                  const __bf16* __restrict__ Wb,
                  const float* __restrict__ beff,
                  float* __restrict__ out) {
  const int lane = threadIdx.x & 63;
  const int wid  = threadIdx.x >> 6;
  const int wr = wid >> 1;          // wave row (0..1)
  const int wc = wid & 1;           // wave col (0..1)
  const int lg = lane >> 4;         // 0..3 (k-chunk group)
  const int lr = lane & 15;         // 0..15 (row of A / col of B)

  const int m0 = blockIdx.x * 128 + wr * 64;
  const int n0 = blockIdx.y * 128 + wc * 64;

  f32x4 acc[4][4];
  #pragma unroll
  for (int mi = 0; mi < 4; ++mi)
    #pragma unroll
    for (int ni = 0; ni < 4; ++ni) {
      f32x4 z;
      z[0] = 0.f; z[1] = 0.f; z[2] = 0.f; z[3] = 0.f;
      acc[mi][ni] = z;
    }

  const float*  xp[4];
  const __bf16* wp[4];
  #pragma unroll
  for (int mi = 0; mi < 4; ++mi)
    xp[mi] = x + (size_t)(m0 + mi * 16 + lr) * Tdim + lg * 8;
  #pragma unroll
  for (int ni = 0; ni < 4; ++ni)
    wp[ni] = Wb + (size_t)(n0 + ni * 16 + lr) * KP + lg * 8;

  const int klim = Tdim - lg * 8;   // this lane-group's A 8-chunk valid iff k0 < klim

  for (int k0 = 0; k0 < KP; k0 += 32) {
    bf16x8 av[4];
    bf16x8 bv[4];
    if (k0 < klim) {
      #pragma unroll
      for (int mi = 0; mi < 4; ++mi) {
        f32x4 a0 = *(const f32x4*)(xp[mi] + k0);
        f32x4 a1 = *(const f32x4*)(xp[mi] + k0 + 4);
        bf16x8 v;
        #pragma unroll
        for (int j = 0; j < 4; ++j) { v[j] = (__bf16)a0[j]; v[j + 4] = (__bf16)a1[j]; }
        av[mi] = v;
      }
    } else {
      #pragma unroll
      for (int mi = 0; mi < 4; ++mi) {
        bf16x8 v;
        #pragma unroll
        for (int j = 0; j < 8; ++j) v[j] = (__bf16)0.0f;
        av[mi] = v;
      }
    }
    #pragma unroll
    for (int ni = 0; ni < 4; ++ni)
      bv[ni] = *(const bf16x8*)(wp[ni] + k0);   // Wb zero-padded: always in-bounds

    #pragma unroll
    for (int mi = 0; mi < 4; ++mi)
      #pragma unroll
      for (int ni = 0; ni < 4; ++ni)
        acc[mi][ni] = __builtin_amdgcn_mfma_f32_16x16x32_bf16(av[mi], bv[ni],
                                                              acc[mi][ni], 0, 0, 0);
  }

  // epilogue: C/D layout col = lane&15, row = (lane>>4)*4 + reg
  #pragma unroll
  for (int ni = 0; ni < 4; ++ni) {
    const int u = n0 + ni * 16 + lr;
    if (u >= Tdim) continue;
    const float bias = beff[u];
    #pragma unroll
    for (int mi = 0; mi < 4; ++mi) {
      const int mb = m0 + mi * 16 + lg * 4;
      #pragma unroll
      for (int j = 0; j < 4; ++j)
        out[(size_t)(mb + j) * Tdim + u] = acc[mi][ni][j] + bias;
    }
  }
}

extern "C" void kernel_launch(void* const* d_in, const int* in_sizes, int n_in,
                              void* d_out, int out_size, void* d_ws, size_t ws_size,
                              hipStream_t stream) {
  const float* x  = (const float*)d_in[0];
  const float* tw = (const float*)d_in[1];
  const float* tb = (const float*)d_in[2];
  const float* sw = (const float*)d_in[3];
  const float* sb = (const float*)d_in[4];
  float* out = (float*)d_out;

  __bf16* Wb  = (__bf16*)d_ws;
  float* beff = (float*)((char*)d_ws + (size_t)WROWS * KP * sizeof(__bf16));

  const int fold_total = WROWS * KP;
  fold_w_kernel<<<dim3((fold_total + 255) / 256), dim3(256), 0, stream>>>(
      tw, tb, sw, sb, Wb, beff);

  const int M = in_sizes[0] / Tdim;            // 16384
  dim3 grid(M / 128, (Tdim + 127) / 128);      // 128 x 6
  dlinear_gemm<<<grid, dim3(256), 0, stream>>>(x, Wb, beff, out);
}

// Round 4
// 61.237 us; speedup vs baseline: 1.2941x; 1.2941x over previous
//
#include <hip/hip_runtime.h>
#include <hip/hip_bf16.h>

// out[b,n,u] = sum_t x[b,n,t] * W_eff[u,t] + b_eff[u]
//   W_eff = Ws + (Wt - Ws) @ A   (A = causal window-mean, window 25)
// M = 16384, T = 720, Kp = 736 (23*32), W rows padded to 768 (zero-filled).
// GEMM: m97 structure — 128x128 tile, 4 waves (2x2), BK=32, single-buffer LDS,
// stage -> barrier -> compute -> barrier. Linear LDS everywhere (no swizzle).
// m0/n0 are BLOCK-level; wave offsets wr*64 / wc*64 appear in fragment
// pointers AND the epilogue (round-3 bug: epilogue omitted them).

#define Tdim  720
#define KP    736
#define WROWS 768
#define NK    23
#define NBLK  6      // n-tiles (720 -> 6 x 128)

using bf16x8 = __attribute__((ext_vector_type(8))) __bf16;
using f32x4  = __attribute__((ext_vector_type(4))) float;

typedef const __attribute__((address_space(1))) void* gas_ptr;
typedef __attribute__((address_space(3))) void* las_ptr;

__global__ void fold_w_kernel(const float* __restrict__ tw,
                              const float* __restrict__ tb,
                              const float* __restrict__ sw,
                              const float* __restrict__ sb,
                              __bf16* __restrict__ Wb,
                              float* __restrict__ beff) {
  int idx = blockIdx.x * 256 + threadIdx.x;
  if (idx >= WROWS * KP) return;
  int u = idx / KP;
  int i = idx - u * KP;
  float w = 0.0f;
  if (u < Tdim && i < Tdim) {
    const float* twr = tw + (size_t)u * Tdim;
    const float* swr = sw + (size_t)u * Tdim;
    int tend = (i + 25 < Tdim) ? (i + 25) : Tdim;
    float acc = 0.0f;
    if (i >= 24) {
      #pragma unroll 5
      for (int t = i; t < tend; ++t) acc += twr[t] - swr[t];
      acc *= 0.04f;
    } else {
      for (int t = i; t < tend; ++t) {
        float c = (t >= 24) ? 0.04f : 1.0f / (float)(t + 1);
        acc += (twr[t] - swr[t]) * c;
      }
    }
    w = swr[i] + acc;
  }
  Wb[idx] = (__bf16)w;
  if (i == 0 && u < Tdim) beff[u] = tb[u] + sb[u];
}

__global__ __launch_bounds__(256, 3)
void dlinear_gemm(const float* __restrict__ x,
                  const __bf16* __restrict__ Wb,
                  const float* __restrict__ beff,
                  float* __restrict__ out, int Mtotal) {
  __shared__ __bf16 As[128 * 32];
  __shared__ __bf16 Bs[128 * 32];

  const int tid  = threadIdx.x;
  const int lane = tid & 63;
  const int wid  = tid >> 6;
  const int wr = wid >> 1, wc = wid & 1;
  const int lg = lane >> 4, lr = lane & 15;

  // XCD-chunked decode (bijective: 768 = 8 XCD * 96): each XCD owns 16 m-blocks;
  // the 6 n-tiles of one m-block are dispatch-adjacent on one XCD -> L2 reuse of x.
  const int bid  = blockIdx.x;
  const int c    = bid >> 3;             // 0..95
  const int mblk = (bid & 7) * 16 + c / NBLK;
  const int nblk = c % NBLK;
  const int m0 = mblk * 128;             // block-level
  const int n0 = nblk * 128;             // block-level

  // ---- A staging: thread -> (row = tid>>1, 16-col half), linear LDS
  const int arow  = tid >> 1;
  const int ahalf = tid & 1;
  const float* abase = x + (size_t)(m0 + arow) * Tdim + ahalf * 16;
  const float* const aclamp = x + (size_t)Mtotal * Tdim - 16;  // last legal 16-f32 base
  __bf16* const awp = &As[arow * 32 + ahalf * 16];

  // ---- B staging: global_load_lds width 16, linear src & dest (m97 pattern)
  const int brow0 = wid * 32 + (lane >> 2);
  const __bf16* bsrc0 = Wb + (size_t)(n0 + brow0) * KP + (lane & 3) * 8;
  const __bf16* bsrc1 = bsrc0 + (size_t)16 * KP;

  // ---- fragment ds_read offsets (linear, wave offsets included HERE)
  const __bf16* arp[4];
  const __bf16* brp[4];
  #pragma unroll
  for (int mi = 0; mi < 4; ++mi) arp[mi] = &As[(wr * 64 + mi * 16 + lr) * 32 + lg * 8];
  #pragma unroll
  for (int ni = 0; ni < 4; ++ni) brp[ni] = &Bs[(wc * 64 + ni * 16 + lr) * 32 + lg * 8];

  f32x4 acc[4][4];
  #pragma unroll
  for (int mi = 0; mi < 4; ++mi)
    #pragma unroll
    for (int ni = 0; ni < 4; ++ni) {
      f32x4 z; z[0] = 0.f; z[1] = 0.f; z[2] = 0.f; z[3] = 0.f;
      acc[mi][ni] = z;
    }

  for (int t = 0; t < NK; ++t) {
    const int k0 = t * 32;

    // stage B (async DMA, drained by the barrier's vmcnt(0))
    __builtin_amdgcn_global_load_lds((gas_ptr)(bsrc0 + k0),
                                     (las_ptr)&Bs[wid * 1024], 16, 0, 0);
    __builtin_amdgcn_global_load_lds((gas_ptr)(bsrc1 + k0),
                                     (las_ptr)&Bs[wid * 1024 + 512], 16, 0, 0);

    // stage A (reg -> cvt -> ds_write, linear)
    const float* p = abase + k0;
    if (p > aclamp) p = aclamp;            // K-tail garbage hits zero-padded B cols
    f32x4 a0 = ((const f32x4*)p)[0];
    f32x4 a1 = ((const f32x4*)p)[1];
    f32x4 a2 = ((const f32x4*)p)[2];
    f32x4 a3 = ((const f32x4*)p)[3];
    bf16x8 v0, v1;
    #pragma unroll
    for (int j = 0; j < 4; ++j) {
      v0[j] = (__bf16)a0[j]; v0[j + 4] = (__bf16)a1[j];
      v1[j] = (__bf16)a2[j]; v1[j + 4] = (__bf16)a3[j];
    }
    *(bf16x8*)awp       = v0;
    *(bf16x8*)(awp + 8) = v1;

    __syncthreads();

    bf16x8 av[4], bv[4];
    #pragma unroll
    for (int mi = 0; mi < 4; ++mi) av[mi] = *(const bf16x8*)arp[mi];
    #pragma unroll
    for (int ni = 0; ni < 4; ++ni) bv[ni] = *(const bf16x8*)brp[ni];
    #pragma unroll
    for (int mi = 0; mi < 4; ++mi)
      #pragma unroll
      for (int ni = 0; ni < 4; ++ni)
        acc[mi][ni] = __builtin_amdgcn_mfma_f32_16x16x32_bf16(av[mi], bv[ni],
                                                              acc[mi][ni], 0, 0, 0);

    __syncthreads();
  }

  // ---- epilogue: C/D layout col = lane&15 (u), row = (lane>>4)*4 + reg (m)
  // FIXED: wave offsets wr*64 / wc*64 restored here.
  #pragma unroll
  for (int ni = 0; ni < 4; ++ni) {
    const int u = n0 + wc * 64 + ni * 16 + lr;
    if (u >= Tdim) continue;
    const float bias = beff[u];
    #pragma unroll
    for (int mi = 0; mi < 4; ++mi) {
      const int mb = m0 + wr * 64 + mi * 16 + lg * 4;
      #pragma unroll
      for (int j = 0; j < 4; ++j)
        out[(size_t)(mb + j) * Tdim + u] = acc[mi][ni][j] + bias;
    }
  }
}

extern "C" void kernel_launch(void* const* d_in, const int* in_sizes, int n_in,
                              void* d_out, int out_size, void* d_ws, size_t ws_size,
                              hipStream_t stream) {
  const float* x  = (const float*)d_in[0];
  const float* tw = (const float*)d_in[1];
  const float* tb = (const float*)d_in[2];
  const float* sw = (const float*)d_in[3];
  const float* sb = (const float*)d_in[4];
  float* out = (float*)d_out;

  __bf16* Wb  = (__bf16*)d_ws;
  float* beff = (float*)((char*)d_ws + (size_t)WROWS * KP * sizeof(__bf16));

  const int fold_total = WROWS * KP;
  fold_w_kernel<<<dim3((fold_total + 255) / 256), dim3(256), 0, stream>>>(
      tw, tb, sw, sb, Wb, beff);

  const int M = in_sizes[0] / Tdim;            // 16384
  dim3 grid((M / 128) * NBLK);                 // 768 blocks, 1D for XCD decode
  dlinear_gemm<<<grid, dim3(256), 0, stream>>>(x, Wb, beff, out, M);
}